// Round 6
// baseline (8427.181 us; speedup 1.0000x reference)
//
#include <hip/hip_runtime.h>
#include <cstdint>
#include <cstddef>

#define EPS_LN 1e-5f

constexpr int TB = 30;    // T
constexpr int CC = 64;    // C
constexpr int DD = 10;    // DAYS
constexpr int WN = 3;     // windows
constexpr int PP = 2016;  // C*(C-1)/2
constexpr int F1 = 4352;  // 2P + 5C
constexpr int PEO = 448;  // 7C
constexpr int CH = 4800;  // CH1

typedef unsigned short u16;
typedef __attribute__((ext_vector_type(8))) short short8;
typedef __attribute__((ext_vector_type(4))) float f32x4;

__device__ __forceinline__ float sigm(float x) { return 1.f / (1.f + expf(-x)); }

__device__ __forceinline__ u16 f2bf(float v) {
    union { float f; uint32_t u; } c; c.f = v;
    uint32_t u = c.u;
    uint32_t r = (u + 0x7FFFu + ((u >> 16) & 1u)) >> 16;
    return (u16)r;
}
__device__ __forceinline__ float bf2f(u16 h) {
    union { uint32_t u; float f; } c; c.u = ((uint32_t)h) << 16;
    return c.f;
}
__device__ __forceinline__ void store_split(u16* __restrict__ hi, u16* __restrict__ lo,
                                            size_t idx, float v) {
    u16 h = f2bf(v);
    hi[idx] = h;
    lo[idx] = f2bf(v - bf2f(h));
}

// async global->LDS, 16B per lane, dest = wave-uniform base + lane*16 [m97/m104]
__device__ __forceinline__ void gll16(const void* g, void* l) {
    __builtin_amdgcn_global_load_lds((const __attribute__((address_space(1))) void*)g,
                                     (__attribute__((address_space(3))) void*)l, 16, 0, 0);
}

// ---------------------------------------------------------------------------
// Stage 1: per-batch window features + pe projection, LN over the 3 windows,
// written as split-bf16 hi/lo planes (N=Bc*3 rows, 4800 cols) row-major.
// ---------------------------------------------------------------------------
__global__ __launch_bounds__(256)
void feat_kernel(const float* __restrict__ x,
                 const float* __restrict__ ln_ts_g, const float* __restrict__ ln_ts_b,
                 const float* __restrict__ pe_w, const float* __restrict__ pe_b,
                 const float* __restrict__ pe_g, const float* __restrict__ pe_beta,
                 u16* __restrict__ hh, u16* __restrict__ hl)
{
    __shared__ float xs[TB * CC];
    __shared__ float mu[WN * CC], sd[WN * CC];
    __shared__ float lg[21], lb[21], pg[3], pb2[3];

    const int tid = threadIdx.x;
    const int b = blockIdx.x;
    const float* xb = x + (size_t)b * (TB * CC);

    for (int i = tid; i < TB * CC; i += 256) xs[i] = xb[i];
    if (tid < 21) { lg[tid] = ln_ts_g[tid]; lb[tid] = ln_ts_b[tid]; }
    if (tid >= 32 && tid < 35) { pg[tid - 32] = pe_g[tid - 32]; pb2[tid - 32] = pe_beta[tid - 32]; }
    __syncthreads();

    if (tid < WN * CC) {
        int w = tid / CC, c = tid % CC;
        float s = 0.f;
#pragma unroll
        for (int d = 0; d < DD; ++d) s += xs[(w * DD + d) * CC + c];
        float m = s * (1.f / DD);
        float q = 0.f;
#pragma unroll
        for (int d = 0; d < DD; ++d) { float t = xs[(w * DD + d) * CC + c] - m; q += t * t; }
        mu[tid] = m;
        sd[tid] = sqrtf(q * (1.f / (DD - 1)));
    }
    __syncthreads();

    const size_t nbase = (size_t)b * WN;

    auto ln3store = [&](float v0, float v1, float v2, int k, int col) {
        float m = (v0 + v1 + v2) * (1.f / 3.f);
        float d0 = v0 - m, d1 = v1 - m, d2 = v2 - m;
        float rs = 1.f / sqrtf((d0 * d0 + d1 * d1 + d2 * d2) * (1.f / 3.f) + EPS_LN);
        store_split(hh, hl, (nbase + 0) * CH + col, d0 * rs * lg[k * 3 + 0] + lb[k * 3 + 0]);
        store_split(hh, hl, (nbase + 1) * CH + col, d1 * rs * lg[k * 3 + 1] + lb[k * 3 + 1]);
        store_split(hh, hl, (nbase + 2) * CH + col, d2 * rs * lg[k * 3 + 2] + lb[k * 3 + 2]);
    };

    // ---- corr (k=0) + cov (k=1): one covariance pass ----
    for (int p = tid; p < PP; p += 256) {
        int i = (int)((2 * CC - 1 - sqrtf((float)((2 * CC - 1) * (2 * CC - 1) - 8 * p))) * 0.5f);
        if (i < 0) i = 0;
        if (i > CC - 2) i = CC - 2;
        while (((i + 1) * (2 * CC - i - 2)) / 2 <= p) ++i;
        while ((i * (2 * CC - i - 1)) / 2 > p) --i;
        int j = i + 1 + (p - (i * (2 * CC - i - 1)) / 2);
        float cv[3], cr[3];
#pragma unroll
        for (int w = 0; w < WN; ++w) {
            float mi = mu[w * CC + i], mj = mu[w * CC + j];
            float s = 0.f;
#pragma unroll
            for (int d = 0; d < DD; ++d)
                s += (xs[(w * DD + d) * CC + i] - mi) * (xs[(w * DD + d) * CC + j] - mj);
            s *= (1.f / (DD - 1));
            cv[w] = s;
            cr[w] = s / (sd[w * CC + i] * sd[w * CC + j]);
        }
        ln3store(cr[0], cr[1], cr[2], 0, p);
        ln3store(cv[0], cv[1], cv[2], 1, PP + p);
    }

    // ---- std / zscore / ret / decay / mu singles (320 cols) ----
    for (int f = tid; f < 5 * CC; f += 256) {
        int k = 2 + f / CC;
        int c = f % CC;
        float v[3];
#pragma unroll
        for (int w = 0; w < WN; ++w) {
            float val;
            if (k == 2) val = sd[w * CC + c];
            else if (k == 3) val = mu[w * CC + c] / sd[w * CC + c];
            else if (k == 4) val = xs[(w * DD + DD - 1) * CC + c] / xs[(w * DD) * CC + c] - 1.f;
            else if (k == 5) {
                float s = 0.f;
#pragma unroll
                for (int d = 0; d < DD; ++d) s += xs[(w * DD + d) * CC + c] * (float)(d + 1);
                val = s * (1.f / 55.f);
            } else val = mu[w * CC + c];
            v[w] = val;
        }
        ln3store(v[0], v[1], v[2], k, 2 * PP + f);
    }

    // ---- pe projection, LN across windows ----
    for (int o = tid; o < PEO; o += 256) {
        const float* wr = pe_w + (size_t)o * (CC * DD);
        float v0 = 0.f, v1 = 0.f, v2 = 0.f;
        for (int c = 0; c < CC; ++c) {
#pragma unroll
            for (int d = 0; d < DD; ++d) {
                float wv = wr[c * DD + d];
                v0 += xs[(0 * DD + d) * CC + c] * wv;
                v1 += xs[(1 * DD + d) * CC + c] * wv;
                v2 += xs[(2 * DD + d) * CC + c] * wv;
            }
        }
        float bo = pe_b[o];
        v0 += bo; v1 += bo; v2 += bo;
        float m = (v0 + v1 + v2) * (1.f / 3.f);
        float d0 = v0 - m, d1 = v1 - m, d2 = v2 - m;
        float rs = 1.f / sqrtf((d0 * d0 + d1 * d1 + d2 * d2) * (1.f / 3.f) + EPS_LN);
        store_split(hh, hl, (nbase + 0) * CH + F1 + o, d0 * rs * pg[0] + pb2[0]);
        store_split(hh, hl, (nbase + 1) * CH + F1 + o, d1 * rs * pg[1] + pb2[1]);
        store_split(hh, hl, (nbase + 2) * CH + F1 + o, d2 * rs * pg[2] + pb2[2]);
    }
}

// ---------------------------------------------------------------------------
// Weight conversion: fp32 (O,K) -> split-bf16 hi/lo (O, Kpad), zero-padded K.
// ---------------------------------------------------------------------------
__global__ __launch_bounds__(256)
void wconv_ker(const float* __restrict__ W, int O, int K, int Kpad,
               u16* __restrict__ Wh, u16* __restrict__ Wl)
{
    int idx = blockIdx.x * 256 + threadIdx.x;
    if (idx >= O * Kpad) return;
    int o = idx / Kpad, k = idx - o * Kpad;
    float v = (k < K) ? W[(size_t)o * K + k] : 0.f;
    u16 h = f2bf(v);
    Wh[idx] = h;
    Wl[idx] = f2bf(v - bf2f(h));
}

// ---------------------------------------------------------------------------
// Split-bf16 MFMA GEMM, global_load_lds staging into 4 LINEAR LDS planes
// [128 rows][32 k] u16 (64B rows) — m97-verified conflict-free layout.
// Optionally fused LN(3-window)+ReLU+split epilogue.
//   Y(N,O) = X(N,K) * W(O,K)^T + bias
// Block tile 128(O) x 126-stride(N) (42 whole row-triples per tile).
// 1D grid with bijective XCD-chunked swizzle [m204]; bx = o-block, by = n-block.
// ---------------------------------------------------------------------------
template<bool FUSE>
__global__ __launch_bounds__(256)
void gemm_mfma(const u16* __restrict__ Whi, const u16* __restrict__ Wlo,
               const u16* __restrict__ Xhi, const u16* __restrict__ Xlo,
               const float* __restrict__ bias,
               const float* __restrict__ lng, const float* __restrict__ lnb,
               int O, int Kpad, int N, int Ntrip, int Opad, int GX,
               u16* __restrict__ Oh, u16* __restrict__ Ol,
               float* __restrict__ Yf)
{
    union SMem {
        struct { u16 A0[128 * 32], A1[128 * 32], B0[128 * 32], B1[128 * 32]; } s; // 32 KB
        float L[128][68];                                                          // 34.8 KB
    };
    __shared__ SMem sm;

    // bijective XCD-chunked swizzle [m204]
    const int nwg = gridDim.x;
    const int orig = blockIdx.x;
    const int q = nwg >> 3, rb = nwg & 7;
    const int xcd = orig & 7, idx = orig >> 3;
    const int wg = (xcd < rb ? xcd * (q + 1) : rb * (q + 1) + (xcd - rb) * q) + idx;
    const int bx = wg % GX;
    const int by = wg / GX;

    const int tid = threadIdx.x;
    const int o0 = bx * 128;
    const int n0 = by * 126;
    const int T0 = by * 42;

    const int w  = tid >> 6;            // wave 0..3
    const int wn = w >> 1, wo = w & 1;  // 2x2 of 64x64
    const int l  = tid & 63;
    const int lr = l & 15, lhi = l >> 4;
    const int srow = l >> 2;            // staging: row-in-16-group
    const int sc8  = (l & 3) * 8;       // staging: k-chunk (8 u16 = 16B)

    f32x4 acc[4][4];
#pragma unroll
    for (int m = 0; m < 4; ++m)
#pragma unroll
        for (int n = 0; n < 4; ++n) acc[m][n] = (f32x4)0.f;

    for (int k0 = 0; k0 < Kpad; k0 += 32) {
        // 32 gll16 insts: planes {A0=Xhi, A1=Xlo, B0=Whi, B1=Wlo}, 8 groups each,
        // each inst stages 16 rows x 64B linearly. Wave w takes insts j*4+w.
#pragma unroll
        for (int j = 0; j < 8; ++j) {
            int blk = j * 4 + w;
            int grp = blk & 7;
            int row = grp * 16 + srow;
            if (blk < 8) {
                size_t g = (size_t)(n0 + row) * Kpad + k0 + sc8;
                gll16(Xhi + g, &sm.s.A0[grp * 512]);
            } else if (blk < 16) {
                size_t g = (size_t)(n0 + row) * Kpad + k0 + sc8;
                gll16(Xlo + g, &sm.s.A1[grp * 512]);
            } else if (blk < 24) {
                size_t g = (size_t)(o0 + row) * Kpad + k0 + sc8;
                gll16(Whi + g, &sm.s.B0[grp * 512]);
            } else {
                size_t g = (size_t)(o0 + row) * Kpad + k0 + sc8;
                gll16(Wlo + g, &sm.s.B1[grp * 512]);
            }
        }
        __syncthreads();   // drains vmcnt (gll) before reads

        short8 ah[4], al[4], bh[4], bl[4];
#pragma unroll
        for (int m = 0; m < 4; ++m) {
            int r = wn * 64 + m * 16 + lr;
            ah[m] = *reinterpret_cast<const short8*>(&sm.s.A0[r * 32 + lhi * 8]);
            al[m] = *reinterpret_cast<const short8*>(&sm.s.A1[r * 32 + lhi * 8]);
        }
#pragma unroll
        for (int n = 0; n < 4; ++n) {
            int r = wo * 64 + n * 16 + lr;
            bh[n] = *reinterpret_cast<const short8*>(&sm.s.B0[r * 32 + lhi * 8]);
            bl[n] = *reinterpret_cast<const short8*>(&sm.s.B1[r * 32 + lhi * 8]);
        }
#pragma unroll
        for (int m = 0; m < 4; ++m)
#pragma unroll
            for (int n = 0; n < 4; ++n) {
                acc[m][n] = __builtin_amdgcn_mfma_f32_16x16x32_bf16(ah[m], bh[n], acc[m][n], 0, 0, 0);
                acc[m][n] = __builtin_amdgcn_mfma_f32_16x16x32_bf16(ah[m], bl[n], acc[m][n], 0, 0, 0);
                acc[m][n] = __builtin_amdgcn_mfma_f32_16x16x32_bf16(al[m], bh[n], acc[m][n], 0, 0, 0);
            }
        __syncthreads();   // LDS free for next stage
    }

    float bv[4];
#pragma unroll
    for (int nf = 0; nf < 4; ++nf) {
        int o = o0 + wo * 64 + nf * 16 + lr;
        bv[nf] = (o < O) ? bias[o] : 0.f;
    }

    if constexpr (!FUSE) {
        // plain fp32 epilogue (proj)
#pragma unroll
        for (int nf = 0; nf < 4; ++nf) {
            int o = o0 + wo * 64 + nf * 16 + lr;
            if (o >= O) continue;
#pragma unroll
            for (int m = 0; m < 4; ++m) {
                int nb = n0 + wn * 64 + m * 16 + lhi * 4;
#pragma unroll
                for (int r = 0; r < 4; ++r) {
                    int n = nb + r;
                    if (n < N) Yf[(size_t)n * O + o] = acc[m][nf][r] + bv[nf];
                }
            }
        }
    } else {
        const float g0 = lng[0], g1 = lng[1], g2 = lng[2];
        const float q0 = lnb[0], q1 = lnb[1], q2 = lnb[2];
        // two o-half passes through the 128x68 fp32 LDS tile
        for (int h = 0; h < 2; ++h) {
            __syncthreads();
            if (wo == h) {
#pragma unroll
                for (int m = 0; m < 4; ++m)
#pragma unroll
                    for (int nf = 0; nf < 4; ++nf)
#pragma unroll
                        for (int r = 0; r < 4; ++r)
                            sm.L[wn * 64 + m * 16 + lhi * 4 + r][nf * 16 + lr] = acc[m][nf][r] + bv[nf];
            }
            __syncthreads();
            for (int it = 0; it < 11; ++it) {   // 42 triples x 64 cols = 2688 items
                int item = it * 256 + tid;
                if (item < 42 * 64) {
                    int tl = item >> 6, c2 = item & 63;
                    int t = T0 + tl;
                    int o = o0 + h * 64 + c2;
                    if (t < Ntrip && o < Opad) {
                        size_t base = (size_t)(3 * t) * Opad + o;
                        if (o >= O) {
                            Oh[base] = 0; Ol[base] = 0;
                            Oh[base + Opad] = 0; Ol[base + Opad] = 0;
                            Oh[base + 2 * (size_t)Opad] = 0; Ol[base + 2 * (size_t)Opad] = 0;
                        } else {
                            float y0 = sm.L[3 * tl + 0][c2];
                            float y1 = sm.L[3 * tl + 1][c2];
                            float y2 = sm.L[3 * tl + 2][c2];
                            float mm = (y0 + y1 + y2) * (1.f / 3.f);
                            float d0 = y0 - mm, d1 = y1 - mm, d2 = y2 - mm;
                            float rs = 1.f / sqrtf((d0 * d0 + d1 * d1 + d2 * d2) * (1.f / 3.f) + EPS_LN);
                            store_split(Oh, Ol, base,                    fmaxf(d0 * rs * g0 + q0, 0.f));
                            store_split(Oh, Ol, base + Opad,             fmaxf(d1 * rs * g1 + q1, 0.f));
                            store_split(Oh, Ol, base + 2 * (size_t)Opad, fmaxf(d2 * rs * g2 + q2, 0.f));
                        }
                    }
                }
            }
        }
    }
}

// ---------------------------------------------------------------------------
// LSTM recurrence + LN over t + final linear.
// ---------------------------------------------------------------------------
__global__ __launch_bounds__(256)
void lstm_ker(const float* __restrict__ gates,   // (Bc*3, 120) fp32
              const float* __restrict__ w_hh, const float* __restrict__ b_hh,
              const float* __restrict__ ln2g, const float* __restrict__ ln2b,
              const float* __restrict__ lin_w, const float* __restrict__ lin_b,
              float* __restrict__ out, int Bc)
{
    __shared__ float whh[120 * 30];
    __shared__ float bhh[120];
    __shared__ float lw[90];
    __shared__ float lg[3], lbv[3];
    __shared__ float hbuf[8][32];

    const int tid = threadIdx.x;
    for (int i = tid; i < 3600; i += 256) whh[i] = w_hh[i];
    if (tid < 120) bhh[tid] = b_hh[tid];
    if (tid < 90) lw[tid] = lin_w[tid];
    if (tid < 3) { lg[tid] = ln2g[tid]; lbv[tid] = ln2b[tid]; }

    const int g = tid >> 5;
    const int u = tid & 31;
    const int bl = blockIdx.x * 8 + g;

    hbuf[g][u] = 0.f;
    __syncthreads();

    float cstate = 0.f;
    float y0 = 0.f, y1 = 0.f, y2 = 0.f;

#pragma unroll
    for (int t = 0; t < 3; ++t) {
        float hn = 0.f;
        if (u < 30) {
            const float* gr = gates + (size_t)(bl * 3 + t) * 120;
            float gi = gr[u]      + bhh[u];
            float gf = gr[30 + u] + bhh[30 + u];
            float gg = gr[60 + u] + bhh[60 + u];
            float go = gr[90 + u] + bhh[90 + u];
            for (int v = 0; v < 30; ++v) {
                float hv = hbuf[g][v];
                gi += whh[u * 30 + v] * hv;
                gf += whh[(30 + u) * 30 + v] * hv;
                gg += whh[(60 + u) * 30 + v] * hv;
                go += whh[(90 + u) * 30 + v] * hv;
            }
            float cn = sigm(gf) * cstate + sigm(gi) * tanhf(gg);
            cstate = cn;
            hn = sigm(go) * tanhf(cn);
        }
        __syncthreads();
        if (u < 30) hbuf[g][u] = hn;
        __syncthreads();
        if (t == 0) y0 = hn; else if (t == 1) y1 = hn; else y2 = hn;
    }

    float acc = 0.f;
    if (u < 30) {
        float m = (y0 + y1 + y2) * (1.f / 3.f);
        float d0 = y0 - m, d1 = y1 - m, d2 = y2 - m;
        float rs = 1.f / sqrtf((d0 * d0 + d1 * d1 + d2 * d2) * (1.f / 3.f) + EPS_LN);
        acc  = (d0 * rs * lg[0] + lbv[0]) * lw[u * 3 + 0];
        acc += (d1 * rs * lg[1] + lbv[1]) * lw[u * 3 + 1];
        acc += (d2 * rs * lg[2] + lbv[2]) * lw[u * 3 + 2];
    }
#pragma unroll
    for (int off = 16; off > 0; off >>= 1)
        acc += __shfl_down(acc, off, 32);
    if (u == 0) out[bl] = acc + lin_b[0];
}

// ---------------------------------------------------------------------------
extern "C" void kernel_launch(void* const* d_in, const int* in_sizes, int n_in,
                              void* d_out, int out_size, void* d_ws, size_t ws_size,
                              hipStream_t stream)
{
    const float* x       = (const float*)d_in[0];
    const float* ln_ts_g = (const float*)d_in[1];
    const float* ln_ts_b = (const float*)d_in[2];
    const float* pe_w    = (const float*)d_in[3];
    const float* pe_b    = (const float*)d_in[4];
    const float* pe_g    = (const float*)d_in[5];
    const float* pe_beta = (const float*)d_in[6];
    const float* e1w = (const float*)d_in[7];  const float* e1b  = (const float*)d_in[8];
    const float* e1g = (const float*)d_in[9];  const float* e1bb = (const float*)d_in[10];
    const float* e2w = (const float*)d_in[11]; const float* e2b  = (const float*)d_in[12];
    const float* e2g = (const float*)d_in[13]; const float* e2bb = (const float*)d_in[14];
    const float* e3w = (const float*)d_in[15]; const float* e3b  = (const float*)d_in[16];
    const float* e3g = (const float*)d_in[17]; const float* e3bb = (const float*)d_in[18];
    const float* e4w = (const float*)d_in[19]; const float* e4b  = (const float*)d_in[20];
    const float* e4g = (const float*)d_in[21]; const float* e4bb = (const float*)d_in[22];
    const float* w_ih = (const float*)d_in[23];
    const float* w_hh = (const float*)d_in[24];
    const float* b_ih = (const float*)d_in[25];
    const float* b_hh = (const float*)d_in[26];
    const float* ln2g = (const float*)d_in[27];
    const float* ln2b = (const float*)d_in[28];
    const float* lin_w = (const float*)d_in[29];
    const float* lin_b = (const float*)d_in[30];
    float* out = (float*)d_out;

    const int Btot = 8192;

    // Layer dims: O, K, Kpad (K padded to mult of 32)
    const int LO[5]  = {2400, 1200, 600, 300, 120};
    const int LK[5]  = {4800, 2400, 1200, 600, 300};
    const int LKP[5] = {4800, 2400, 1216, 608, 320};
    const float* LW[5] = {e1w, e2w, e3w, e4w, w_ih};

    // ---- workspace carve (u16 units; every sub-offset stays 16B-aligned) ----
    u16* wp = (u16*)d_ws;
    u16* Wh[5]; u16* Wl[5];
    size_t wcount = 0;
    for (int i = 0; i < 5; ++i) {
        Wh[i] = wp + wcount; wcount += (size_t)LO[i] * LKP[i];
        Wl[i] = wp + wcount; wcount += (size_t)LO[i] * LKP[i];
    }
    const size_t wbytes = wcount * sizeof(u16);   // ~61.4 MB

    // per-batch-elem activation bytes: Xa(4800 hi/lo) + Xb(2400 hi/lo) + Yf(120 f32)
    const size_t per_b = (size_t)3 * 4800 * 2 * 2 + (size_t)3 * 2400 * 2 * 2 + (size_t)3 * 128 * 4;
    const size_t slack = (size_t)128 * (4800 + 2400) * 2 * 2 + 4096;  // +128 staging over-read rows
    int Bc = 2048;
    while (Bc > 128 && wbytes + slack + (size_t)Bc * per_b > ws_size) Bc >>= 1;
    const int n_chunks = Btot / Bc;
    const int N = Bc * 3;

    u16* Xah = wp + wcount;            wcount += (size_t)(N + 128) * 4800;
    u16* Xal = wp + wcount;            wcount += (size_t)(N + 128) * 4800;
    u16* Xbh = wp + wcount;            wcount += (size_t)(N + 128) * 2400;
    u16* Xbl = wp + wcount;            wcount += (size_t)(N + 128) * 2400;
    float* Yf = (float*)(wp + wcount); // N*120 fp32 (proj gates)

    // ---- convert weights once per launch ----
    for (int i = 0; i < 5; ++i) {
        int tot = LO[i] * LKP[i];
        wconv_ker<<<(tot + 255) / 256, 256, 0, stream>>>(LW[i], LO[i], LK[i], LKP[i], Wh[i], Wl[i]);
    }

    const int GY = (N + 125) / 126;   // 126-row stride tiles (42 triples each)

    for (int c = 0; c < n_chunks; ++c) {
        const int b0 = c * Bc;
        feat_kernel<<<Bc, 256, 0, stream>>>(x + (size_t)b0 * TB * CC,
                                            ln_ts_g, ln_ts_b, pe_w, pe_b, pe_g, pe_beta,
                                            Xah, Xal);

        // enc1: (2400,4800) -> LN+ReLU fused -> Xb (pitch 2400)
        gemm_mfma<true><<<19 * GY, 256, 0, stream>>>(
            Wh[0], Wl[0], Xah, Xal, e1b, e1g, e1bb,
            2400, 4800, N, Bc, 2400, 19, Xbh, Xbl, nullptr);

        // enc2: (1200,2400) -> Xa (pitch 1216, pad cols zeroed)
        gemm_mfma<true><<<10 * GY, 256, 0, stream>>>(
            Wh[1], Wl[1], Xbh, Xbl, e2b, e2g, e2bb,
            1200, 2400, N, Bc, 1216, 10, Xah, Xal, nullptr);

        // enc3: (600,1216) -> Xb (pitch 608)
        gemm_mfma<true><<<5 * GY, 256, 0, stream>>>(
            Wh[2], Wl[2], Xah, Xal, e3b, e3g, e3bb,
            600, 1216, N, Bc, 608, 5, Xbh, Xbl, nullptr);

        // enc4: (300,608) -> Xa (pitch 320)
        gemm_mfma<true><<<3 * GY, 256, 0, stream>>>(
            Wh[3], Wl[3], Xbh, Xbl, e4b, e4g, e4bb,
            300, 608, N, Bc, 320, 3, Xah, Xal, nullptr);

        // proj: gates = e4 @ w_ih^T + b_ih  (120,320) -> fp32 Yf
        gemm_mfma<false><<<1 * GY, 256, 0, stream>>>(
            Wh[4], Wl[4], Xah, Xal, b_ih, nullptr, nullptr,
            120, 320, N, Bc, 120, 1, nullptr, nullptr, Yf);

        lstm_ker<<<Bc / 8, 256, 0, stream>>>(Yf, w_hh, b_hh, ln2g, ln2b,
                                             lin_w, lin_b, out + b0, Bc);
    }
}

// Round 10
// 6964.738 us; speedup vs baseline: 1.2100x; 1.2100x over previous
//
#include <hip/hip_runtime.h>
#include <cstdint>
#include <cstddef>

#define EPS_LN 1e-5f

constexpr int TB = 30;    // T
constexpr int CC = 64;    // C
constexpr int DD = 10;    // DAYS
constexpr int WN = 3;     // windows
constexpr int PP = 2016;  // C*(C-1)/2
constexpr int F1 = 4352;  // 2P + 5C
constexpr int PEO = 448;  // 7C
constexpr int CH = 4800;  // CH1

typedef unsigned short u16;
typedef __attribute__((ext_vector_type(8))) short short8;
typedef __attribute__((ext_vector_type(4))) float f32x4;

__device__ __forceinline__ float sigm(float x) { return 1.f / (1.f + expf(-x)); }

__device__ __forceinline__ u16 f2bf(float v) {
    union { float f; uint32_t u; } c; c.f = v;
    uint32_t u = c.u;
    uint32_t r = (u + 0x7FFFu + ((u >> 16) & 1u)) >> 16;
    return (u16)r;
}
__device__ __forceinline__ float bf2f(u16 h) {
    union { uint32_t u; float f; } c; c.u = ((uint32_t)h) << 16;
    return c.f;
}
__device__ __forceinline__ void store_split(u16* __restrict__ hi, u16* __restrict__ lo,
                                            size_t idx, float v) {
    u16 h = f2bf(v);
    hi[idx] = h;
    lo[idx] = f2bf(v - bf2f(h));
}

// ---------------------------------------------------------------------------
// Stage 1: per-batch window features + pe projection, LN over the 3 windows,
// written as split-bf16 hi/lo planes (N=Bc*3 rows, 4800 cols) row-major.
// ---------------------------------------------------------------------------
__global__ __launch_bounds__(256)
void feat_kernel(const float* __restrict__ x,
                 const float* __restrict__ ln_ts_g, const float* __restrict__ ln_ts_b,
                 const float* __restrict__ pe_w, const float* __restrict__ pe_b,
                 const float* __restrict__ pe_g, const float* __restrict__ pe_beta,
                 u16* __restrict__ hh, u16* __restrict__ hl)
{
    __shared__ float xs[TB * CC];
    __shared__ float mu[WN * CC], sd[WN * CC];
    __shared__ float lg[21], lb[21], pg[3], pb2[3];

    const int tid = threadIdx.x;
    const int b = blockIdx.x;
    const float* xb = x + (size_t)b * (TB * CC);

    for (int i = tid; i < TB * CC; i += 256) xs[i] = xb[i];
    if (tid < 21) { lg[tid] = ln_ts_g[tid]; lb[tid] = ln_ts_b[tid]; }
    if (tid >= 32 && tid < 35) { pg[tid - 32] = pe_g[tid - 32]; pb2[tid - 32] = pe_beta[tid - 32]; }
    __syncthreads();

    if (tid < WN * CC) {
        int w = tid / CC, c = tid % CC;
        float s = 0.f;
#pragma unroll
        for (int d = 0; d < DD; ++d) s += xs[(w * DD + d) * CC + c];
        float m = s * (1.f / DD);
        float q = 0.f;
#pragma unroll
        for (int d = 0; d < DD; ++d) { float t = xs[(w * DD + d) * CC + c] - m; q += t * t; }
        mu[tid] = m;
        sd[tid] = sqrtf(q * (1.f / (DD - 1)));
    }
    __syncthreads();

    const size_t nbase = (size_t)b * WN;

    auto ln3store = [&](float v0, float v1, float v2, int k, int col) {
        float m = (v0 + v1 + v2) * (1.f / 3.f);
        float d0 = v0 - m, d1 = v1 - m, d2 = v2 - m;
        float rs = 1.f / sqrtf((d0 * d0 + d1 * d1 + d2 * d2) * (1.f / 3.f) + EPS_LN);
        store_split(hh, hl, (nbase + 0) * CH + col, d0 * rs * lg[k * 3 + 0] + lb[k * 3 + 0]);
        store_split(hh, hl, (nbase + 1) * CH + col, d1 * rs * lg[k * 3 + 1] + lb[k * 3 + 1]);
        store_split(hh, hl, (nbase + 2) * CH + col, d2 * rs * lg[k * 3 + 2] + lb[k * 3 + 2]);
    };

    // ---- corr (k=0) + cov (k=1): one covariance pass ----
    for (int p = tid; p < PP; p += 256) {
        int i = (int)((2 * CC - 1 - sqrtf((float)((2 * CC - 1) * (2 * CC - 1) - 8 * p))) * 0.5f);
        if (i < 0) i = 0;
        if (i > CC - 2) i = CC - 2;
        while (((i + 1) * (2 * CC - i - 2)) / 2 <= p) ++i;
        while ((i * (2 * CC - i - 1)) / 2 > p) --i;
        int j = i + 1 + (p - (i * (2 * CC - i - 1)) / 2);
        float cv[3], cr[3];
#pragma unroll
        for (int w = 0; w < WN; ++w) {
            float mi = mu[w * CC + i], mj = mu[w * CC + j];
            float s = 0.f;
#pragma unroll
            for (int d = 0; d < DD; ++d)
                s += (xs[(w * DD + d) * CC + i] - mi) * (xs[(w * DD + d) * CC + j] - mj);
            s *= (1.f / (DD - 1));
            cv[w] = s;
            cr[w] = s / (sd[w * CC + i] * sd[w * CC + j]);
        }
        ln3store(cr[0], cr[1], cr[2], 0, p);
        ln3store(cv[0], cv[1], cv[2], 1, PP + p);
    }

    // ---- std / zscore / ret / decay / mu singles (320 cols) ----
    for (int f = tid; f < 5 * CC; f += 256) {
        int k = 2 + f / CC;
        int c = f % CC;
        float v[3];
#pragma unroll
        for (int w = 0; w < WN; ++w) {
            float val;
            if (k == 2) val = sd[w * CC + c];
            else if (k == 3) val = mu[w * CC + c] / sd[w * CC + c];
            else if (k == 4) val = xs[(w * DD + DD - 1) * CC + c] / xs[(w * DD) * CC + c] - 1.f;
            else if (k == 5) {
                float s = 0.f;
#pragma unroll
                for (int d = 0; d < DD; ++d) s += xs[(w * DD + d) * CC + c] * (float)(d + 1);
                val = s * (1.f / 55.f);
            } else val = mu[w * CC + c];
            v[w] = val;
        }
        ln3store(v[0], v[1], v[2], k, 2 * PP + f);
    }

    // ---- pe projection, LN across windows ----
    for (int o = tid; o < PEO; o += 256) {
        const float* wr = pe_w + (size_t)o * (CC * DD);
        float v0 = 0.f, v1 = 0.f, v2 = 0.f;
        for (int c = 0; c < CC; ++c) {
#pragma unroll
            for (int d = 0; d < DD; ++d) {
                float wv = wr[c * DD + d];
                v0 += xs[(0 * DD + d) * CC + c] * wv;
                v1 += xs[(1 * DD + d) * CC + c] * wv;
                v2 += xs[(2 * DD + d) * CC + c] * wv;
            }
        }
        float bo = pe_b[o];
        v0 += bo; v1 += bo; v2 += bo;
        float m = (v0 + v1 + v2) * (1.f / 3.f);
        float d0 = v0 - m, d1 = v1 - m, d2 = v2 - m;
        float rs = 1.f / sqrtf((d0 * d0 + d1 * d1 + d2 * d2) * (1.f / 3.f) + EPS_LN);
        store_split(hh, hl, (nbase + 0) * CH + F1 + o, d0 * rs * pg[0] + pb2[0]);
        store_split(hh, hl, (nbase + 1) * CH + F1 + o, d1 * rs * pg[1] + pb2[1]);
        store_split(hh, hl, (nbase + 2) * CH + F1 + o, d2 * rs * pg[2] + pb2[2]);
    }
}

// ---------------------------------------------------------------------------
// Weight conversion: fp32 (O,K) -> split-bf16 hi/lo (O, Kpad), zero-padded K.
// ---------------------------------------------------------------------------
__global__ __launch_bounds__(256)
void wconv_ker(const float* __restrict__ W, int O, int K, int Kpad,
               u16* __restrict__ Wh, u16* __restrict__ Wl)
{
    int idx = blockIdx.x * 256 + threadIdx.x;
    if (idx >= O * Kpad) return;
    int o = idx / Kpad, k = idx - o * Kpad;
    float v = (k < K) ? W[(size_t)o * K + k] : 0.f;
    u16 h = f2bf(v);
    Wh[idx] = h;
    Wl[idx] = f2bf(v - bf2f(h));
}

// ---------------------------------------------------------------------------
// Split-bf16 MFMA GEMM, round-4-proven staging: vectorized global int4 loads
// -> ds_write into 4 LDS planes [128][40] u16 (80B pitch; odd bank stride 20
// cycles all 8 bank-sets over 8 rows -> conflict-free ds_read_b128).
// Optionally fused LN(3-window)+ReLU+split epilogue.
//   Y(N,O) = X(N,K) * W(O,K)^T + bias
// Block tile 128(O) x 126-stride(N) (42 whole row-triples per tile).
// 2D grid dim3(GX, GY), x fastest -> consecutive blocks share the X panel.
// ---------------------------------------------------------------------------
template<bool FUSE>
__global__ __launch_bounds__(256)
void gemm_mfma(const u16* __restrict__ Whi, const u16* __restrict__ Wlo,
               const u16* __restrict__ Xhi, const u16* __restrict__ Xlo,
               const float* __restrict__ bias,
               const float* __restrict__ lng, const float* __restrict__ lnb,
               int O, int Kpad, int N, int Ntrip, int Opad,
               u16* __restrict__ Oh, u16* __restrict__ Ol,
               float* __restrict__ Yf)
{
    constexpr int LDW = 40;   // 80B pitch
    union SMem {
        struct { u16 Ah[128][LDW], Al[128][LDW], Bh[128][LDW], Bl[128][LDW]; } s; // 40 KB
        float L[128][68];                                                          // 34.8 KB
    };
    __shared__ SMem sm;

    const int tid = threadIdx.x;
    const int o0 = blockIdx.x * 128;
    const int n0 = blockIdx.y * 126;
    const int T0 = blockIdx.y * 42;

    const int w  = tid >> 6;            // wave 0..3
    const int wn = w >> 1, wo = w & 1;  // 2x2 of 64x64
    const int l  = tid & 63;
    const int lr = l & 15, lhi = l >> 4;
    const int sr = tid >> 2;            // staging row 0..63
    const int sq = tid & 3;             // staging 16B chunk

    f32x4 acc[4][4];
#pragma unroll
    for (int m = 0; m < 4; ++m)
#pragma unroll
        for (int n = 0; n < 4; ++n) acc[m][n] = (f32x4)0.f;

    for (int k0 = 0; k0 < Kpad; k0 += 32) {
        // X tile (128 rows x 32 k), hi+lo  (rows beyond N read workspace slack)
#pragma unroll
        for (int rep = 0; rep < 2; ++rep) {
            int row = rep * 64 + sr;
            size_t g = (size_t)(n0 + row) * Kpad + k0 + sq * 8;
            *reinterpret_cast<int4*>(&sm.s.Ah[row][sq * 8]) = *reinterpret_cast<const int4*>(Xhi + g);
            *reinterpret_cast<int4*>(&sm.s.Al[row][sq * 8]) = *reinterpret_cast<const int4*>(Xlo + g);
        }
        // W tile (128 rows x 32 k), hi+lo, zero rows past O
#pragma unroll
        for (int rep = 0; rep < 2; ++rep) {
            int row = rep * 64 + sr;
            int orow = o0 + row;
            int4 vh = make_int4(0, 0, 0, 0), vl = make_int4(0, 0, 0, 0);
            if (orow < O) {
                size_t g = (size_t)orow * Kpad + k0 + sq * 8;
                vh = *reinterpret_cast<const int4*>(Whi + g);
                vl = *reinterpret_cast<const int4*>(Wlo + g);
            }
            *reinterpret_cast<int4*>(&sm.s.Bh[row][sq * 8]) = vh;
            *reinterpret_cast<int4*>(&sm.s.Bl[row][sq * 8]) = vl;
        }
        __syncthreads();

        short8 ah[4], al[4], bh[4], bl[4];
#pragma unroll
        for (int m = 0; m < 4; ++m) {
            int r = wn * 64 + m * 16 + lr;
            ah[m] = *reinterpret_cast<const short8*>(&sm.s.Ah[r][lhi * 8]);
            al[m] = *reinterpret_cast<const short8*>(&sm.s.Al[r][lhi * 8]);
        }
#pragma unroll
        for (int n = 0; n < 4; ++n) {
            int r = wo * 64 + n * 16 + lr;
            bh[n] = *reinterpret_cast<const short8*>(&sm.s.Bh[r][lhi * 8]);
            bl[n] = *reinterpret_cast<const short8*>(&sm.s.Bl[r][lhi * 8]);
        }
#pragma unroll
        for (int m = 0; m < 4; ++m)
#pragma unroll
            for (int n = 0; n < 4; ++n) {
                acc[m][n] = __builtin_amdgcn_mfma_f32_16x16x32_bf16(ah[m], bh[n], acc[m][n], 0, 0, 0);
                acc[m][n] = __builtin_amdgcn_mfma_f32_16x16x32_bf16(ah[m], bl[n], acc[m][n], 0, 0, 0);
                acc[m][n] = __builtin_amdgcn_mfma_f32_16x16x32_bf16(al[m], bh[n], acc[m][n], 0, 0, 0);
            }
        __syncthreads();
    }

    float bv[4];
#pragma unroll
    for (int nf = 0; nf < 4; ++nf) {
        int o = o0 + wo * 64 + nf * 16 + lr;
        bv[nf] = (o < O) ? bias[o] : 0.f;
    }

    if constexpr (!FUSE) {
        // plain fp32 epilogue (proj)
#pragma unroll
        for (int nf = 0; nf < 4; ++nf) {
            int o = o0 + wo * 64 + nf * 16 + lr;
            if (o >= O) continue;
#pragma unroll
            for (int m = 0; m < 4; ++m) {
                int nb = n0 + wn * 64 + m * 16 + lhi * 4;
#pragma unroll
                for (int r = 0; r < 4; ++r) {
                    int n = nb + r;
                    if (n < N) Yf[(size_t)n * O + o] = acc[m][nf][r] + bv[nf];
                }
            }
        }
    } else {
        const float g0 = lng[0], g1 = lng[1], g2 = lng[2];
        const float q0 = lnb[0], q1 = lnb[1], q2 = lnb[2];
        // two o-half passes through the 128x68 fp32 LDS tile
        for (int h = 0; h < 2; ++h) {
            __syncthreads();
            if (wo == h) {
#pragma unroll
                for (int m = 0; m < 4; ++m)
#pragma unroll
                    for (int nf = 0; nf < 4; ++nf)
#pragma unroll
                        for (int r = 0; r < 4; ++r)
                            sm.L[wn * 64 + m * 16 + lhi * 4 + r][nf * 16 + lr] = acc[m][nf][r] + bv[nf];
            }
            __syncthreads();
            for (int it = 0; it < 11; ++it) {   // 42 triples x 64 cols = 2688 items
                int item = it * 256 + tid;
                if (item < 42 * 64) {
                    int tl = item >> 6, c2 = item & 63;
                    int t = T0 + tl;
                    int o = o0 + h * 64 + c2;
                    if (t < Ntrip && o < Opad) {
                        size_t base = (size_t)(3 * t) * Opad + o;
                        if (o >= O) {
                            Oh[base] = 0; Ol[base] = 0;
                            Oh[base + Opad] = 0; Ol[base + Opad] = 0;
                            Oh[base + 2 * (size_t)Opad] = 0; Ol[base + 2 * (size_t)Opad] = 0;
                        } else {
                            float y0 = sm.L[3 * tl + 0][c2];
                            float y1 = sm.L[3 * tl + 1][c2];
                            float y2 = sm.L[3 * tl + 2][c2];
                            float mm = (y0 + y1 + y2) * (1.f / 3.f);
                            float d0 = y0 - mm, d1 = y1 - mm, d2 = y2 - mm;
                            float rs = 1.f / sqrtf((d0 * d0 + d1 * d1 + d2 * d2) * (1.f / 3.f) + EPS_LN);
                            store_split(Oh, Ol, base,                    fmaxf(d0 * rs * g0 + q0, 0.f));
                            store_split(Oh, Ol, base + Opad,             fmaxf(d1 * rs * g1 + q1, 0.f));
                            store_split(Oh, Ol, base + 2 * (size_t)Opad, fmaxf(d2 * rs * g2 + q2, 0.f));
                        }
                    }
                }
            }
        }
    }
}

// ---------------------------------------------------------------------------
// LSTM recurrence + LN over t + final linear.
// ---------------------------------------------------------------------------
__global__ __launch_bounds__(256)
void lstm_ker(const float* __restrict__ gates,   // (Bc*3, 120) fp32
              const float* __restrict__ w_hh, const float* __restrict__ b_hh,
              const float* __restrict__ ln2g, const float* __restrict__ ln2b,
              const float* __restrict__ lin_w, const float* __restrict__ lin_b,
              float* __restrict__ out, int Bc)
{
    __shared__ float whh[120 * 30];
    __shared__ float bhh[120];
    __shared__ float lw[90];
    __shared__ float lg[3], lbv[3];
    __shared__ float hbuf[8][32];

    const int tid = threadIdx.x;
    for (int i = tid; i < 3600; i += 256) whh[i] = w_hh[i];
    if (tid < 120) bhh[tid] = b_hh[tid];
    if (tid < 90) lw[tid] = lin_w[tid];
    if (tid < 3) { lg[tid] = ln2g[tid]; lbv[tid] = ln2b[tid]; }

    const int g = tid >> 5;
    const int u = tid & 31;
    const int bl = blockIdx.x * 8 + g;

    hbuf[g][u] = 0.f;
    __syncthreads();

    float cstate = 0.f;
    float y0 = 0.f, y1 = 0.f, y2 = 0.f;

#pragma unroll
    for (int t = 0; t < 3; ++t) {
        float hn = 0.f;
        if (u < 30) {
            const float* gr = gates + (size_t)(bl * 3 + t) * 120;
            float gi = gr[u]      + bhh[u];
            float gf = gr[30 + u] + bhh[30 + u];
            float gg = gr[60 + u] + bhh[60 + u];
            float go = gr[90 + u] + bhh[90 + u];
            for (int v = 0; v < 30; ++v) {
                float hv = hbuf[g][v];
                gi += whh[u * 30 + v] * hv;
                gf += whh[(30 + u) * 30 + v] * hv;
                gg += whh[(60 + u) * 30 + v] * hv;
                go += whh[(90 + u) * 30 + v] * hv;
            }
            float cn = sigm(gf) * cstate + sigm(gi) * tanhf(gg);
            cstate = cn;
            hn = sigm(go) * tanhf(cn);
        }
        __syncthreads();
        if (u < 30) hbuf[g][u] = hn;
        __syncthreads();
        if (t == 0) y0 = hn; else if (t == 1) y1 = hn; else y2 = hn;
    }

    float acc = 0.f;
    if (u < 30) {
        float m = (y0 + y1 + y2) * (1.f / 3.f);
        float d0 = y0 - m, d1 = y1 - m, d2 = y2 - m;
        float rs = 1.f / sqrtf((d0 * d0 + d1 * d1 + d2 * d2) * (1.f / 3.f) + EPS_LN);
        acc  = (d0 * rs * lg[0] + lbv[0]) * lw[u * 3 + 0];
        acc += (d1 * rs * lg[1] + lbv[1]) * lw[u * 3 + 1];
        acc += (d2 * rs * lg[2] + lbv[2]) * lw[u * 3 + 2];
    }
#pragma unroll
    for (int off = 16; off > 0; off >>= 1)
        acc += __shfl_down(acc, off, 32);
    if (u == 0) out[bl] = acc + lin_b[0];
}

// ---------------------------------------------------------------------------
extern "C" void kernel_launch(void* const* d_in, const int* in_sizes, int n_in,
                              void* d_out, int out_size, void* d_ws, size_t ws_size,
                              hipStream_t stream)
{
    const float* x       = (const float*)d_in[0];
    const float* ln_ts_g = (const float*)d_in[1];
    const float* ln_ts_b = (const float*)d_in[2];
    const float* pe_w    = (const float*)d_in[3];
    const float* pe_b    = (const float*)d_in[4];
    const float* pe_g    = (const float*)d_in[5];
    const float* pe_beta = (const float*)d_in[6];
    const float* e1w = (const float*)d_in[7];  const float* e1b  = (const float*)d_in[8];
    const float* e1g = (const float*)d_in[9];  const float* e1bb = (const float*)d_in[10];
    const float* e2w = (const float*)d_in[11]; const float* e2b  = (const float*)d_in[12];
    const float* e2g = (const float*)d_in[13]; const float* e2bb = (const float*)d_in[14];
    const float* e3w = (const float*)d_in[15]; const float* e3b  = (const float*)d_in[16];
    const float* e3g = (const float*)d_in[17]; const float* e3bb = (const float*)d_in[18];
    const float* e4w = (const float*)d_in[19]; const float* e4b  = (const float*)d_in[20];
    const float* e4g = (const float*)d_in[21]; const float* e4bb = (const float*)d_in[22];
    const float* w_ih = (const float*)d_in[23];
    const float* w_hh = (const float*)d_in[24];
    const float* b_ih = (const float*)d_in[25];
    const float* b_hh = (const float*)d_in[26];
    const float* ln2g = (const float*)d_in[27];
    const float* ln2b = (const float*)d_in[28];
    const float* lin_w = (const float*)d_in[29];
    const float* lin_b = (const float*)d_in[30];
    float* out = (float*)d_out;

    const int Btot = 8192;

    // Layer dims: O, K, Kpad (K padded to mult of 32)
    const int LO[5]  = {2400, 1200, 600, 300, 120};
    const int LK[5]  = {4800, 2400, 1200, 600, 300};
    const int LKP[5] = {4800, 2400, 1216, 608, 320};
    const float* LW[5] = {e1w, e2w, e3w, e4w, w_ih};

    // ---- workspace carve (u16 units; every sub-offset stays 16B-aligned) ----
    u16* wp = (u16*)d_ws;
    u16* Wh[5]; u16* Wl[5];
    size_t wcount = 0;
    for (int i = 0; i < 5; ++i) {
        Wh[i] = wp + wcount; wcount += (size_t)LO[i] * LKP[i];
        Wl[i] = wp + wcount; wcount += (size_t)LO[i] * LKP[i];
    }
    const size_t wbytes = wcount * sizeof(u16);   // ~61.4 MB

    // per-batch-elem activation bytes: Xa(4800 hi/lo) + Xb(2400 hi/lo) + Yf(120 f32)
    const size_t per_b = (size_t)3 * 4800 * 2 * 2 + (size_t)3 * 2400 * 2 * 2 + (size_t)3 * 128 * 4;
    const size_t slack = (size_t)128 * (4800 + 2400) * 2 * 2 + 4096;  // +128 staging over-read rows
    int Bc = 2048;
    while (Bc > 128 && wbytes + slack + (size_t)Bc * per_b > ws_size) Bc >>= 1;
    const int n_chunks = Btot / Bc;
    const int N = Bc * 3;

    u16* Xah = wp + wcount;            wcount += (size_t)(N + 128) * 4800;
    u16* Xal = wp + wcount;            wcount += (size_t)(N + 128) * 4800;
    u16* Xbh = wp + wcount;            wcount += (size_t)(N + 128) * 2400;
    u16* Xbl = wp + wcount;            wcount += (size_t)(N + 128) * 2400;
    float* Yf = (float*)(wp + wcount); // N*120 fp32 (proj gates)

    // ---- convert weights once per launch ----
    for (int i = 0; i < 5; ++i) {
        int tot = LO[i] * LKP[i];
        wconv_ker<<<(tot + 255) / 256, 256, 0, stream>>>(LW[i], LO[i], LK[i], LKP[i], Wh[i], Wl[i]);
    }

    const int GY = (N + 125) / 126;   // 126-row stride tiles (42 triples each)

    for (int c = 0; c < n_chunks; ++c) {
        const int b0 = c * Bc;
        feat_kernel<<<Bc, 256, 0, stream>>>(x + (size_t)b0 * TB * CC,
                                            ln_ts_g, ln_ts_b, pe_w, pe_b, pe_g, pe_beta,
                                            Xah, Xal);

        // enc1: (2400,4800) -> LN+ReLU fused -> Xb (pitch 2400)
        gemm_mfma<true><<<dim3(19, GY), 256, 0, stream>>>(
            Wh[0], Wl[0], Xah, Xal, e1b, e1g, e1bb,
            2400, 4800, N, Bc, 2400, Xbh, Xbl, nullptr);

        // enc2: (1200,2400) -> Xa (pitch 1216, pad cols zeroed)
        gemm_mfma<true><<<dim3(10, GY), 256, 0, stream>>>(
            Wh[1], Wl[1], Xbh, Xbl, e2b, e2g, e2bb,
            1200, 2400, N, Bc, 1216, Xah, Xal, nullptr);

        // enc3: (600,1216) -> Xb (pitch 608)
        gemm_mfma<true><<<dim3(5, GY), 256, 0, stream>>>(
            Wh[2], Wl[2], Xah, Xal, e3b, e3g, e3bb,
            600, 1216, N, Bc, 608, Xbh, Xbl, nullptr);

        // enc4: (300,608) -> Xa (pitch 320)
        gemm_mfma<true><<<dim3(3, GY), 256, 0, stream>>>(
            Wh[3], Wl[3], Xbh, Xbl, e4b, e4g, e4bb,
            300, 608, N, Bc, 320, Xah, Xal, nullptr);

        // proj: gates = e4 @ w_ih^T + b_ih  (120,320) -> fp32 Yf
        gemm_mfma<false><<<dim3(1, GY), 256, 0, stream>>>(
            Wh[4], Wl[4], Xah, Xal, b_ih, nullptr, nullptr,
            120, 320, N, Bc, 120, nullptr, nullptr, Yf);

        lstm_ker<<<Bc / 8, 256, 0, stream>>>(Yf, w_hh, b_hh, ln2g, ln2b,
                                             lin_w, lin_b, out + b0, Bc);
    }
}

// Round 11
// 5717.094 us; speedup vs baseline: 1.4740x; 1.2182x over previous
//
#include <hip/hip_runtime.h>
#include <cstdint>
#include <cstddef>

#define EPS_LN 1e-5f

constexpr int TB = 30;    // T
constexpr int CC = 64;    // C
constexpr int DD = 10;    // DAYS
constexpr int WN = 3;     // windows
constexpr int PP = 2016;  // C*(C-1)/2
constexpr int F1 = 4352;  // 2P + 5C
constexpr int PEO = 448;  // 7C
constexpr int CH = 4800;  // CH1

typedef unsigned short u16;
typedef __attribute__((ext_vector_type(8))) short short8;
typedef __attribute__((ext_vector_type(4))) float f32x4;

__device__ __forceinline__ float sigm(float x) { return 1.f / (1.f + expf(-x)); }

__device__ __forceinline__ u16 f2bf(float v) {
    union { float f; uint32_t u; } c; c.f = v;
    uint32_t u = c.u;
    uint32_t r = (u + 0x7FFFu + ((u >> 16) & 1u)) >> 16;
    return (u16)r;
}
__device__ __forceinline__ float bf2f(u16 h) {
    union { uint32_t u; float f; } c; c.u = ((uint32_t)h) << 16;
    return c.f;
}
__device__ __forceinline__ void store_split(u16* __restrict__ hi, u16* __restrict__ lo,
                                            size_t idx, float v) {
    u16 h = f2bf(v);
    hi[idx] = h;
    lo[idx] = f2bf(v - bf2f(h));
}

// async global->LDS, 16B per lane, dest = wave-uniform base + lane*16 [m97/m104]
__device__ __forceinline__ void gll16(const void* g, void* l) {
    __builtin_amdgcn_global_load_lds((const __attribute__((address_space(1))) void*)g,
                                     (__attribute__((address_space(3))) void*)l, 16, 0, 0);
}

// ---------------------------------------------------------------------------
// Stage 1: per-batch window features + pe projection, LN over the 3 windows,
// written as split-bf16 hi/lo planes (N=Bc*3 rows, 4800 cols) row-major.
// ---------------------------------------------------------------------------
__global__ __launch_bounds__(256)
void feat_kernel(const float* __restrict__ x,
                 const float* __restrict__ ln_ts_g, const float* __restrict__ ln_ts_b,
                 const float* __restrict__ pe_w, const float* __restrict__ pe_b,
                 const float* __restrict__ pe_g, const float* __restrict__ pe_beta,
                 u16* __restrict__ hh, u16* __restrict__ hl)
{
    __shared__ float xs[TB * CC];
    __shared__ float mu[WN * CC], sd[WN * CC];
    __shared__ float lg[21], lb[21], pg[3], pb2[3];

    const int tid = threadIdx.x;
    const int b = blockIdx.x;
    const float* xb = x + (size_t)b * (TB * CC);

    for (int i = tid; i < TB * CC; i += 256) xs[i] = xb[i];
    if (tid < 21) { lg[tid] = ln_ts_g[tid]; lb[tid] = ln_ts_b[tid]; }
    if (tid >= 32 && tid < 35) { pg[tid - 32] = pe_g[tid - 32]; pb2[tid - 32] = pe_beta[tid - 32]; }
    __syncthreads();

    if (tid < WN * CC) {
        int w = tid / CC, c = tid % CC;
        float s = 0.f;
#pragma unroll
        for (int d = 0; d < DD; ++d) s += xs[(w * DD + d) * CC + c];
        float m = s * (1.f / DD);
        float q = 0.f;
#pragma unroll
        for (int d = 0; d < DD; ++d) { float t = xs[(w * DD + d) * CC + c] - m; q += t * t; }
        mu[tid] = m;
        sd[tid] = sqrtf(q * (1.f / (DD - 1)));
    }
    __syncthreads();

    const size_t nbase = (size_t)b * WN;

    auto ln3store = [&](float v0, float v1, float v2, int k, int col) {
        float m = (v0 + v1 + v2) * (1.f / 3.f);
        float d0 = v0 - m, d1 = v1 - m, d2 = v2 - m;
        float rs = 1.f / sqrtf((d0 * d0 + d1 * d1 + d2 * d2) * (1.f / 3.f) + EPS_LN);
        store_split(hh, hl, (nbase + 0) * CH + col, d0 * rs * lg[k * 3 + 0] + lb[k * 3 + 0]);
        store_split(hh, hl, (nbase + 1) * CH + col, d1 * rs * lg[k * 3 + 1] + lb[k * 3 + 1]);
        store_split(hh, hl, (nbase + 2) * CH + col, d2 * rs * lg[k * 3 + 2] + lb[k * 3 + 2]);
    };

    // ---- corr (k=0) + cov (k=1): one covariance pass ----
    for (int p = tid; p < PP; p += 256) {
        int i = (int)((2 * CC - 1 - sqrtf((float)((2 * CC - 1) * (2 * CC - 1) - 8 * p))) * 0.5f);
        if (i < 0) i = 0;
        if (i > CC - 2) i = CC - 2;
        while (((i + 1) * (2 * CC - i - 2)) / 2 <= p) ++i;
        while ((i * (2 * CC - i - 1)) / 2 > p) --i;
        int j = i + 1 + (p - (i * (2 * CC - i - 1)) / 2);
        float cv[3], cr[3];
#pragma unroll
        for (int w = 0; w < WN; ++w) {
            float mi = mu[w * CC + i], mj = mu[w * CC + j];
            float s = 0.f;
#pragma unroll
            for (int d = 0; d < DD; ++d)
                s += (xs[(w * DD + d) * CC + i] - mi) * (xs[(w * DD + d) * CC + j] - mj);
            s *= (1.f / (DD - 1));
            cv[w] = s;
            cr[w] = s / (sd[w * CC + i] * sd[w * CC + j]);
        }
        ln3store(cr[0], cr[1], cr[2], 0, p);
        ln3store(cv[0], cv[1], cv[2], 1, PP + p);
    }

    // ---- std / zscore / ret / decay / mu singles (320 cols) ----
    for (int f = tid; f < 5 * CC; f += 256) {
        int k = 2 + f / CC;
        int c = f % CC;
        float v[3];
#pragma unroll
        for (int w = 0; w < WN; ++w) {
            float val;
            if (k == 2) val = sd[w * CC + c];
            else if (k == 3) val = mu[w * CC + c] / sd[w * CC + c];
            else if (k == 4) val = xs[(w * DD + DD - 1) * CC + c] / xs[(w * DD) * CC + c] - 1.f;
            else if (k == 5) {
                float s = 0.f;
#pragma unroll
                for (int d = 0; d < DD; ++d) s += xs[(w * DD + d) * CC + c] * (float)(d + 1);
                val = s * (1.f / 55.f);
            } else val = mu[w * CC + c];
            v[w] = val;
        }
        ln3store(v[0], v[1], v[2], k, 2 * PP + f);
    }

    // ---- pe projection, LN across windows ----
    for (int o = tid; o < PEO; o += 256) {
        const float* wr = pe_w + (size_t)o * (CC * DD);
        float v0 = 0.f, v1 = 0.f, v2 = 0.f;
        for (int c = 0; c < CC; ++c) {
#pragma unroll
            for (int d = 0; d < DD; ++d) {
                float wv = wr[c * DD + d];
                v0 += xs[(0 * DD + d) * CC + c] * wv;
                v1 += xs[(1 * DD + d) * CC + c] * wv;
                v2 += xs[(2 * DD + d) * CC + c] * wv;
            }
        }
        float bo = pe_b[o];
        v0 += bo; v1 += bo; v2 += bo;
        float m = (v0 + v1 + v2) * (1.f / 3.f);
        float d0 = v0 - m, d1 = v1 - m, d2 = v2 - m;
        float rs = 1.f / sqrtf((d0 * d0 + d1 * d1 + d2 * d2) * (1.f / 3.f) + EPS_LN);
        store_split(hh, hl, (nbase + 0) * CH + F1 + o, d0 * rs * pg[0] + pb2[0]);
        store_split(hh, hl, (nbase + 1) * CH + F1 + o, d1 * rs * pg[1] + pb2[1]);
        store_split(hh, hl, (nbase + 2) * CH + F1 + o, d2 * rs * pg[2] + pb2[2]);
    }
}

// ---------------------------------------------------------------------------
// Weight conversion: fp32 (O,K) -> split-bf16 hi/lo (O, Kpad), zero-padded K.
// ---------------------------------------------------------------------------
__global__ __launch_bounds__(256)
void wconv_ker(const float* __restrict__ W, int O, int K, int Kpad,
               u16* __restrict__ Wh, u16* __restrict__ Wl)
{
    int idx = blockIdx.x * 256 + threadIdx.x;
    if (idx >= O * Kpad) return;
    int o = idx / Kpad, k = idx - o * Kpad;
    float v = (k < K) ? W[(size_t)o * K + k] : 0.f;
    u16 h = f2bf(v);
    Wh[idx] = h;
    Wl[idx] = f2bf(v - bf2f(h));
}

// ---------------------------------------------------------------------------
// Split-bf16 MFMA GEMM — R5's best-measured fused variant (gll16 staging,
// 128B interleaved hi/lo rows, XOR chunk pre-swizzle on the global source,
// linear LDS dest [m104/m173]) + m204 bijective XCD-chunked block swizzle:
// x-fastest flattening chunked per XCD -> each XCD runs contiguous by-groups,
// keeping its X panel L2-resident while W streams via shared L3.
//   Y(N,O) = X(N,K) * W(O,K)^T + bias, optional fused LN(3)+ReLU+split.
// Block tile 128(O) x 126-stride(N) (42 whole row-triples per tile).
// ---------------------------------------------------------------------------
template<bool FUSE>
__global__ __launch_bounds__(256)
void gemm_mfma(const u16* __restrict__ Whi, const u16* __restrict__ Wlo,
               const u16* __restrict__ Xhi, const u16* __restrict__ Xlo,
               const float* __restrict__ bias,
               const float* __restrict__ lng, const float* __restrict__ lnb,
               int O, int Kpad, int N, int Ntrip, int Opad, int GX,
               u16* __restrict__ Oh, u16* __restrict__ Ol,
               float* __restrict__ Yf)
{
    union SMem {
        struct { u16 A[128 * 64]; u16 B[128 * 64]; } s;  // 32 KB staging
        float L[128][68];                                 // 34.8 KB epilogue tile
    };
    __shared__ SMem sm;

    // bijective XCD-chunked swizzle [m204]: XCD k owns a contiguous wg range
    const int nwg = gridDim.x;
    const int orig = blockIdx.x;
    const int q = nwg >> 3, rb = nwg & 7;
    const int xcd = orig & 7, idx = orig >> 3;
    const int wg = (xcd < rb ? xcd * (q + 1) : rb * (q + 1) + (xcd - rb) * q) + idx;
    const int bx = wg % GX;   // o-block (x-fastest: same-by blocks contiguous)
    const int by = wg / GX;

    const int tid = threadIdx.x;
    const int o0 = bx * 128;
    const int n0 = by * 126;
    const int T0 = by * 42;

    const int w  = tid >> 6;            // wave 0..3
    const int wn = w >> 1, wo = w & 1;  // 2x2 of 64x64
    const int l  = tid & 63;
    const int lr = l & 15, lhi = l >> 4;
    const int rg = l >> 3, sl = l & 7;  // staging: row-in-8-group, lds slot
    const int ck = sl ^ rg;             // source chunk (0..3 hi, 4..7 lo)

    f32x4 acc[4][4];
#pragma unroll
    for (int m = 0; m < 4; ++m)
#pragma unroll
        for (int n = 0; n < 4; ++n) acc[m][n] = (f32x4)0.f;

    for (int k0 = 0; k0 < Kpad; k0 += 32) {
#pragma unroll
        for (int j = 0; j < 8; ++j) {
            int blk = j * 4 + w;   // 0..31: 16 A-blocks then 16 B-blocks
            if (blk < 16) {
                int row = blk * 8 + rg;
                size_t gb = (size_t)(n0 + row) * Kpad + k0;
                const u16* src = (ck < 4) ? (Xhi + gb + ck * 8) : (Xlo + gb + (ck - 4) * 8);
                gll16(src, &sm.s.A[blk * 512]);
            } else {
                int row = (blk - 16) * 8 + rg;
                size_t gb = (size_t)(o0 + row) * Kpad + k0;
                const u16* src = (ck < 4) ? (Whi + gb + ck * 8) : (Wlo + gb + (ck - 4) * 8);
                gll16(src, &sm.s.B[(blk - 16) * 512]);
            }
        }
        __syncthreads();   // drains vmcnt (gll) before reads

        short8 ah[4], al[4], bh[4], bl[4];
#pragma unroll
        for (int m = 0; m < 4; ++m) {
            int r = wn * 64 + m * 16 + lr;
            int shi = lhi ^ (r & 7);
            int slo = (4 ^ lhi) ^ (r & 7);
            ah[m] = *reinterpret_cast<const short8*>(&sm.s.A[r * 64 + shi * 8]);
            al[m] = *reinterpret_cast<const short8*>(&sm.s.A[r * 64 + slo * 8]);
        }
#pragma unroll
        for (int n = 0; n < 4; ++n) {
            int r = wo * 64 + n * 16 + lr;
            int shi = lhi ^ (r & 7);
            int slo = (4 ^ lhi) ^ (r & 7);
            bh[n] = *reinterpret_cast<const short8*>(&sm.s.B[r * 64 + shi * 8]);
            bl[n] = *reinterpret_cast<const short8*>(&sm.s.B[r * 64 + slo * 8]);
        }
#pragma unroll
        for (int m = 0; m < 4; ++m)
#pragma unroll
            for (int n = 0; n < 4; ++n) {
                acc[m][n] = __builtin_amdgcn_mfma_f32_16x16x32_bf16(ah[m], bh[n], acc[m][n], 0, 0, 0);
                acc[m][n] = __builtin_amdgcn_mfma_f32_16x16x32_bf16(ah[m], bl[n], acc[m][n], 0, 0, 0);
                acc[m][n] = __builtin_amdgcn_mfma_f32_16x16x32_bf16(al[m], bh[n], acc[m][n], 0, 0, 0);
            }
        __syncthreads();   // LDS free for next stage
    }

    float bv[4];
#pragma unroll
    for (int nf = 0; nf < 4; ++nf) {
        int o = o0 + wo * 64 + nf * 16 + lr;
        bv[nf] = (o < O) ? bias[o] : 0.f;
    }

    if constexpr (!FUSE) {
        // plain fp32 epilogue (proj): overlap rows double-written benignly
#pragma unroll
        for (int nf = 0; nf < 4; ++nf) {
            int o = o0 + wo * 64 + nf * 16 + lr;
            if (o >= O) continue;
#pragma unroll
            for (int m = 0; m < 4; ++m) {
                int nb = n0 + wn * 64 + m * 16 + lhi * 4;
#pragma unroll
                for (int r = 0; r < 4; ++r) {
                    int n = nb + r;
                    if (n < N) Yf[(size_t)n * O + o] = acc[m][nf][r] + bv[nf];
                }
            }
        }
    } else {
        const float g0 = lng[0], g1 = lng[1], g2 = lng[2];
        const float q0 = lnb[0], q1 = lnb[1], q2 = lnb[2];
        // two o-half passes through the 128x68 fp32 LDS tile
        for (int h = 0; h < 2; ++h) {
            __syncthreads();
            if (wo == h) {
#pragma unroll
                for (int m = 0; m < 4; ++m)
#pragma unroll
                    for (int nf = 0; nf < 4; ++nf)
#pragma unroll
                        for (int r = 0; r < 4; ++r)
                            sm.L[wn * 64 + m * 16 + lhi * 4 + r][nf * 16 + lr] = acc[m][nf][r] + bv[nf];
            }
            __syncthreads();
            for (int it = 0; it < 11; ++it) {   // 42 triples x 64 cols = 2688 items
                int item = it * 256 + tid;
                if (item < 42 * 64) {
                    int tl = item >> 6, c2 = item & 63;
                    int t = T0 + tl;
                    int o = o0 + h * 64 + c2;
                    if (t < Ntrip && o < Opad) {
                        size_t base = (size_t)(3 * t) * Opad + o;
                        if (o >= O) {
                            Oh[base] = 0; Ol[base] = 0;
                            Oh[base + Opad] = 0; Ol[base + Opad] = 0;
                            Oh[base + 2 * (size_t)Opad] = 0; Ol[base + 2 * (size_t)Opad] = 0;
                        } else {
                            float y0 = sm.L[3 * tl + 0][c2];
                            float y1 = sm.L[3 * tl + 1][c2];
                            float y2 = sm.L[3 * tl + 2][c2];
                            float mm = (y0 + y1 + y2) * (1.f / 3.f);
                            float d0 = y0 - mm, d1 = y1 - mm, d2 = y2 - mm;
                            float rs = 1.f / sqrtf((d0 * d0 + d1 * d1 + d2 * d2) * (1.f / 3.f) + EPS_LN);
                            store_split(Oh, Ol, base,                    fmaxf(d0 * rs * g0 + q0, 0.f));
                            store_split(Oh, Ol, base + Opad,             fmaxf(d1 * rs * g1 + q1, 0.f));
                            store_split(Oh, Ol, base + 2 * (size_t)Opad, fmaxf(d2 * rs * g2 + q2, 0.f));
                        }
                    }
                }
            }
        }
    }
}

// ---------------------------------------------------------------------------
// LSTM recurrence + LN over t + final linear.
// ---------------------------------------------------------------------------
__global__ __launch_bounds__(256)
void lstm_ker(const float* __restrict__ gates,   // (Bc*3, 120) fp32
              const float* __restrict__ w_hh, const float* __restrict__ b_hh,
              const float* __restrict__ ln2g, const float* __restrict__ ln2b,
              const float* __restrict__ lin_w, const float* __restrict__ lin_b,
              float* __restrict__ out, int Bc)
{
    __shared__ float whh[120 * 30];
    __shared__ float bhh[120];
    __shared__ float lw[90];
    __shared__ float lg[3], lbv[3];
    __shared__ float hbuf[8][32];

    const int tid = threadIdx.x;
    for (int i = tid; i < 3600; i += 256) whh[i] = w_hh[i];
    if (tid < 120) bhh[tid] = b_hh[tid];
    if (tid < 90) lw[tid] = lin_w[tid];
    if (tid < 3) { lg[tid] = ln2g[tid]; lbv[tid] = ln2b[tid]; }

    const int g = tid >> 5;
    const int u = tid & 31;
    const int bl = blockIdx.x * 8 + g;

    hbuf[g][u] = 0.f;
    __syncthreads();

    float cstate = 0.f;
    float y0 = 0.f, y1 = 0.f, y2 = 0.f;

#pragma unroll
    for (int t = 0; t < 3; ++t) {
        float hn = 0.f;
        if (u < 30) {
            const float* gr = gates + (size_t)(bl * 3 + t) * 120;
            float gi = gr[u]      + bhh[u];
            float gf = gr[30 + u] + bhh[30 + u];
            float gg = gr[60 + u] + bhh[60 + u];
            float go = gr[90 + u] + bhh[90 + u];
            for (int v = 0; v < 30; ++v) {
                float hv = hbuf[g][v];
                gi += whh[u * 30 + v] * hv;
                gf += whh[(30 + u) * 30 + v] * hv;
                gg += whh[(60 + u) * 30 + v] * hv;
                go += whh[(90 + u) * 30 + v] * hv;
            }
            float cn = sigm(gf) * cstate + sigm(gi) * tanhf(gg);
            cstate = cn;
            hn = sigm(go) * tanhf(cn);
        }
        __syncthreads();
        if (u < 30) hbuf[g][u] = hn;
        __syncthreads();
        if (t == 0) y0 = hn; else if (t == 1) y1 = hn; else y2 = hn;
    }

    float acc = 0.f;
    if (u < 30) {
        float m = (y0 + y1 + y2) * (1.f / 3.f);
        float d0 = y0 - m, d1 = y1 - m, d2 = y2 - m;
        float rs = 1.f / sqrtf((d0 * d0 + d1 * d1 + d2 * d2) * (1.f / 3.f) + EPS_LN);
        acc  = (d0 * rs * lg[0] + lbv[0]) * lw[u * 3 + 0];
        acc += (d1 * rs * lg[1] + lbv[1]) * lw[u * 3 + 1];
        acc += (d2 * rs * lg[2] + lbv[2]) * lw[u * 3 + 2];
    }
#pragma unroll
    for (int off = 16; off > 0; off >>= 1)
        acc += __shfl_down(acc, off, 32);
    if (u == 0) out[bl] = acc + lin_b[0];
}

// ---------------------------------------------------------------------------
extern "C" void kernel_launch(void* const* d_in, const int* in_sizes, int n_in,
                              void* d_out, int out_size, void* d_ws, size_t ws_size,
                              hipStream_t stream)
{
    const float* x       = (const float*)d_in[0];
    const float* ln_ts_g = (const float*)d_in[1];
    const float* ln_ts_b = (const float*)d_in[2];
    const float* pe_w    = (const float*)d_in[3];
    const float* pe_b    = (const float*)d_in[4];
    const float* pe_g    = (const float*)d_in[5];
    const float* pe_beta = (const float*)d_in[6];
    const float* e1w = (const float*)d_in[7];  const float* e1b  = (const float*)d_in[8];
    const float* e1g = (const float*)d_in[9];  const float* e1bb = (const float*)d_in[10];
    const float* e2w = (const float*)d_in[11]; const float* e2b  = (const float*)d_in[12];
    const float* e2g = (const float*)d_in[13]; const float* e2bb = (const float*)d_in[14];
    const float* e3w = (const float*)d_in[15]; const float* e3b  = (const float*)d_in[16];
    const float* e3g = (const float*)d_in[17]; const float* e3bb = (const float*)d_in[18];
    const float* e4w = (const float*)d_in[19]; const float* e4b  = (const float*)d_in[20];
    const float* e4g = (const float*)d_in[21]; const float* e4bb = (const float*)d_in[22];
    const float* w_ih = (const float*)d_in[23];
    const float* w_hh = (const float*)d_in[24];
    const float* b_ih = (const float*)d_in[25];
    const float* b_hh = (const float*)d_in[26];
    const float* ln2g = (const float*)d_in[27];
    const float* ln2b = (const float*)d_in[28];
    const float* lin_w = (const float*)d_in[29];
    const float* lin_b = (const float*)d_in[30];
    float* out = (float*)d_out;

    const int Btot = 8192;

    // Layer dims: O, K, Kpad (K padded to mult of 32)
    const int LO[5]  = {2400, 1200, 600, 300, 120};
    const int LK[5]  = {4800, 2400, 1200, 600, 300};
    const int LKP[5] = {4800, 2400, 1216, 608, 320};
    const float* LW[5] = {e1w, e2w, e3w, e4w, w_ih};

    // ---- workspace carve (u16 units; every sub-offset stays 16B-aligned) ----
    u16* wp = (u16*)d_ws;
    u16* Wh[5]; u16* Wl[5];
    size_t wcount = 0;
    for (int i = 0; i < 5; ++i) {
        Wh[i] = wp + wcount; wcount += (size_t)LO[i] * LKP[i];
        Wl[i] = wp + wcount; wcount += (size_t)LO[i] * LKP[i];
    }
    const size_t wbytes = wcount * sizeof(u16);   // ~61.4 MB

    // per-batch-elem activation bytes: Xa(4800 hi/lo) + Xb(2400 hi/lo) + Yf(120 f32)
    const size_t per_b = (size_t)3 * 4800 * 2 * 2 + (size_t)3 * 2400 * 2 * 2 + (size_t)3 * 128 * 4;
    const size_t slack = (size_t)128 * (4800 + 2400) * 2 * 2 + 4096;  // +128 staging over-read rows
    int Bc = 2048;
    while (Bc > 128 && wbytes + slack + (size_t)Bc * per_b > ws_size) Bc >>= 1;
    const int n_chunks = Btot / Bc;
    const int N = Bc * 3;

    u16* Xah = wp + wcount;            wcount += (size_t)(N + 128) * 4800;
    u16* Xal = wp + wcount;            wcount += (size_t)(N + 128) * 4800;
    u16* Xbh = wp + wcount;            wcount += (size_t)(N + 128) * 2400;
    u16* Xbl = wp + wcount;            wcount += (size_t)(N + 128) * 2400;
    float* Yf = (float*)(wp + wcount); // N*120 fp32 (proj gates)

    // ---- convert weights once per launch ----
    for (int i = 0; i < 5; ++i) {
        int tot = LO[i] * LKP[i];
        wconv_ker<<<(tot + 255) / 256, 256, 0, stream>>>(LW[i], LO[i], LK[i], LKP[i], Wh[i], Wl[i]);
    }

    const int GY = (N + 125) / 126;   // 126-row stride tiles (42 triples each)

    for (int c = 0; c < n_chunks; ++c) {
        const int b0 = c * Bc;
        feat_kernel<<<Bc, 256, 0, stream>>>(x + (size_t)b0 * TB * CC,
                                            ln_ts_g, ln_ts_b, pe_w, pe_b, pe_g, pe_beta,
                                            Xah, Xal);

        // enc1: (2400,4800) -> LN+ReLU fused -> Xb (pitch 2400)
        gemm_mfma<true><<<19 * GY, 256, 0, stream>>>(
            Wh[0], Wl[0], Xah, Xal, e1b, e1g, e1bb,
            2400, 4800, N, Bc, 2400, 19, Xbh, Xbl, nullptr);

        // enc2: (1200,2400) -> Xa (pitch 1216, pad cols zeroed)
        gemm_mfma<true><<<10 * GY, 256, 0, stream>>>(
            Wh[1], Wl[1], Xbh, Xbl, e2b, e2g, e2bb,
            1200, 2400, N, Bc, 1216, 10, Xah, Xal, nullptr);

        // enc3: (600,1216) -> Xb (pitch 608)
        gemm_mfma<true><<<5 * GY, 256, 0, stream>>>(
            Wh[2], Wl[2], Xah, Xal, e3b, e3g, e3bb,
            600, 1216, N, Bc, 608, 5, Xbh, Xbl, nullptr);

        // enc4: (300,608) -> Xa (pitch 320)
        gemm_mfma<true><<<3 * GY, 256, 0, stream>>>(
            Wh[3], Wl[3], Xbh, Xbl, e4b, e4g, e4bb,
            300, 608, N, Bc, 320, 3, Xah, Xal, nullptr);

        // proj: gates = e4 @ w_ih^T + b_ih  (120,320) -> fp32 Yf
        gemm_mfma<false><<<1 * GY, 256, 0, stream>>>(
            Wh[4], Wl[4], Xah, Xal, b_ih, nullptr, nullptr,
            120, 320, N, Bc, 120, 1, nullptr, nullptr, Yf);

        lstm_ker<<<Bc / 8, 256, 0, stream>>>(Yf, w_hh, b_hh, ln2g, ln2b,
                                             lin_w, lin_b, out + b0, Bc);
    }
}